// Round 3
// baseline (849.494 us; speedup 1.0000x reference)
//
#include <hip/hip_runtime.h>

#define NN 200000
#define NE 200000
#define HD 256

typedef __attribute__((ext_vector_type(8))) short short8;
typedef __attribute__((ext_vector_type(4))) short short4v;
typedef __attribute__((ext_vector_type(4))) float f32x4;

static __device__ __forceinline__ unsigned short f2bf(float f) {
  unsigned u = __float_as_uint(f);
  u = (u + 0x7FFFu + ((u >> 16) & 1u)) >> 16;
  return (unsigned short)u;
}
static __device__ __forceinline__ float bf2f(unsigned short u) {
  return __uint_as_float(((unsigned)u) << 16);
}
static __device__ __forceinline__ float sigmoidf_(float x) {
  return 1.0f / (1.0f + __expf(-x));
}
static __device__ __forceinline__ float tanhf_(float x) {
  return 2.0f / (1.0f + __expf(-2.0f * x)) - 1.0f;
}
static __device__ __forceinline__ void atomAddF(float* p, float v) {
  __hip_atomic_fetch_add(p, v, __ATOMIC_RELAXED, __HIP_MEMORY_SCOPE_AGENT);
}
static __device__ __forceinline__ int atomAddI(int* p, int v) {
  return __hip_atomic_fetch_add(p, v, __ATOMIC_RELAXED, __HIP_MEMORY_SCOPE_AGENT);
}

#if __has_builtin(__builtin_amdgcn_global_load_lds)
#define HAVE_GLDS 1
static __device__ __forceinline__ void gload_lds16(const void* g, void* l) {
  __builtin_amdgcn_global_load_lds(
      (const __attribute__((address_space(1))) void*)g,
      (__attribute__((address_space(3))) void*)l, 16, 0, 0);
}
#endif

// ws layout (bytes)
#define OFF_WFB    0u           // bf16[256*256]
#define OFF_BP     131072u      // packed B fragments: bf16[16*48*64*8] = 786432 B
#define OFF_BPERM  917504u      // f32[768]
#define OFF_ROWPTR 920576u      // int[NN+1]
#define OFF_NEXT   1720832u     // int[NN]
#define OFF_SLOT   2520832u     // int[NE]
#define OFF_PSRC   3320832u     // int[NE]
#define OFF_BSUM   4120832u     // int[256]
#define OFF_ZERO   4121856u     // 1024 B of zeros
#define OFF_FC     4122880u     // bf16[NE*HD]
#define WS_NEED    106522880ull
#define WS_NEED_FB 1048576ull   // fallback path needs < 1 MB

// --------- prep (fast path): Wfb bf16; B fragment-packed; bias gate-permuted --
// Bp element o = ((kc*48 + tt)*64 + lane)*8 + e  <->  B[row_p][kk] where
//   row_p = tt*16 + (lane&15) (gate-interleaved tile tt), kk = kc*32+(lane>>4)*8+e,
//   B = [W_iou_perm ; U_iou_perm] along K (512).
__global__ __launch_bounds__(256) void prep_kernel(
    const float* __restrict__ Ufw, const float* __restrict__ Wiou,
    const float* __restrict__ Uiou, const float* __restrict__ biou,
    unsigned short* __restrict__ Wfb, unsigned short* __restrict__ Bp,
    float* __restrict__ bperm) {
  int idx = blockIdx.x * 256 + threadIdx.x;
  if (idx < 65536) {
    Wfb[idx] = f2bf(Ufw[idx]);
  } else if (idx < 458752) {
    int o = idx - 65536;
    int kc = o / 24576;
    int rem = o - kc * 24576;
    int tt = rem / 512;
    int rem2 = rem - tt * 512;
    int ln = rem2 >> 3, e = rem2 & 7;
    int cc = ln & 15, kgp = ln >> 4;
    int kk = kc * 32 + kgp * 8 + e;
    int g = tt % 3, tj = tt / 3;
    int orow = g * 256 + tj * 16 + cc;
    float v = (kk < 256) ? Wiou[orow * 256 + kk] : Uiou[orow * 256 + (kk - 256)];
    Bp[o] = f2bf(v);
  } else if (idx < 459520) {
    int j2 = idx - 458752;
    int T = j2 >> 4, cc = j2 & 15;
    int g = T % 3, tj = T / 3;
    bperm[j2] = biou[g * 256 + tj * 16 + cc];
  }
}

// --------- prep (fallback): plain gate-permuted row-major W/U ---------------
__global__ __launch_bounds__(256) void prep_fb_kernel(
    const float* __restrict__ Ufw, const float* __restrict__ Wiou,
    const float* __restrict__ Uiou, const float* __restrict__ biou,
    unsigned short* __restrict__ Wfb, unsigned short* __restrict__ Wioub,
    unsigned short* __restrict__ Uioub, float* __restrict__ bperm) {
  int idx = blockIdx.x * 256 + threadIdx.x;
  if (idx < 65536) {
    Wfb[idx] = f2bf(Ufw[idx]);
  } else if (idx < 262144) {
    int i2 = idx - 65536;
    int rp = i2 >> 8, k = i2 & 255;
    int T = rp >> 4, cc = rp & 15;
    int g = T % 3, tj = T / 3;
    Wioub[i2] = f2bf(Wiou[(g * 256 + tj * 16 + cc) * 256 + k]);
  } else if (idx < 458752) {
    int i2 = idx - 262144;
    int rp = i2 >> 8, k = i2 & 255;
    int T = rp >> 4, cc = rp & 15;
    int g = T % 3, tj = T / 3;
    Uioub[i2] = f2bf(Uiou[(g * 256 + tj * 16 + cc) * 256 + k]);
  } else if (idx < 459520) {
    int j2 = idx - 458752;
    int T = j2 >> 4, cc = j2 & 15;
    int g = T % 3, tj = T / 3;
    bperm[j2] = biou[g * 256 + tj * 16 + cc];
  }
}

// ---------------- CSR build ----------------
__global__ __launch_bounds__(256) void hist_kernel(const int* __restrict__ edst,
                                                   int* __restrict__ cnt) {
  int e = blockIdx.x * 256 + threadIdx.x;
  if (e < NE) atomAddI(&cnt[edst[e]], 1);
}

__global__ __launch_bounds__(256) void scan_part(const int* __restrict__ cnt,
                                                 int* __restrict__ rp,
                                                 int* __restrict__ bsum) {
  __shared__ int sd[256];
  int t = threadIdx.x;
  int base = blockIdx.x * 1024 + t * 4;
  int v0 = (base + 0 < NN) ? cnt[base + 0] : 0;
  int v1 = (base + 1 < NN) ? cnt[base + 1] : 0;
  int v2 = (base + 2 < NN) ? cnt[base + 2] : 0;
  int v3 = (base + 3 < NN) ? cnt[base + 3] : 0;
  int s = v0 + v1 + v2 + v3;
  sd[t] = s;
  __syncthreads();
  for (int off = 1; off < 256; off <<= 1) {
    int add = (t >= off) ? sd[t - off] : 0;
    __syncthreads();
    sd[t] += add;
    __syncthreads();
  }
  int run = sd[t] - s;  // exclusive
  if (base + 0 < NN) rp[base + 0] = run; run += v0;
  if (base + 1 < NN) rp[base + 1] = run; run += v1;
  if (base + 2 < NN) rp[base + 2] = run; run += v2;
  if (base + 3 < NN) rp[base + 3] = run;
  if (t == 255) bsum[blockIdx.x] = sd[255];
}

__global__ __launch_bounds__(256) void scan_top(int* __restrict__ bsum,
                                                int* __restrict__ rp, int nb) {
  __shared__ int sd[256];
  int t = threadIdx.x;
  int v = (t < nb) ? bsum[t] : 0;
  sd[t] = v;
  __syncthreads();
  for (int off = 1; off < 256; off <<= 1) {
    int add = (t >= off) ? sd[t - off] : 0;
    __syncthreads();
    sd[t] += add;
    __syncthreads();
  }
  bsum[t] = sd[t] - v;  // exclusive block offsets
  if (t == 0) rp[NN] = NE;
}

__global__ __launch_bounds__(256) void scan_add(int* __restrict__ rp,
                                                const int* __restrict__ bsum,
                                                int* __restrict__ nxt) {
  int t = threadIdx.x;
  int base = blockIdx.x * 1024 + t * 4;
  int off = bsum[blockIdx.x];
#pragma unroll
  for (int j = 0; j < 4; ++j) {
    int i = base + j;
    if (i < NN) {
      int val = rp[i] + off;
      rp[i] = val;
      nxt[i] = val;
    }
  }
}

__global__ __launch_bounds__(256) void scatter_kernel(
    const int* __restrict__ esrc, const int* __restrict__ edst,
    int* __restrict__ nxt, int* __restrict__ slotArr, int* __restrict__ psrc) {
  int e = blockIdx.x * 256 + threadIdx.x;
  if (e < NE) {
    int d = edst[e];
    int pos = atomAddI(&nxt[d], 1);
    slotArr[e] = pos;
    psrc[pos] = esrc[e];
  }
}

// ---------------- edge kernel: fc[slot] = sigmoid(h[src]@Ufw^T+b)*c[src] ------
#define F_AS 72
#define F_BS 72

__global__ __launch_bounds__(256) void edge_fc_kernel(
    const float* __restrict__ h, const float* __restrict__ c,
    const unsigned short* __restrict__ Wfb, const float* __restrict__ Ufb,
    const int* __restrict__ esrc, const int* __restrict__ slotArr,
    unsigned short* __restrict__ fcb) {
  __shared__ __align__(16) unsigned short Als[64 * F_AS];
  __shared__ __align__(16) unsigned short Bls[256 * F_BS];
  __shared__ int srcl[64], slotl[64];

  const int tid = threadIdx.x;
  const int e0 = blockIdx.x * 64;
  if (tid < 64) { srcl[tid] = esrc[e0 + tid]; slotl[tid] = slotArr[e0 + tid]; }
  __syncthreads();

  const int lane = tid & 63;
  const int wv = tid >> 6;
  const int wm = wv >> 1, wn = wv & 1;
  const int cbase = lane & 15;
  const int kg = lane >> 4;

  f32x4 acc[2][8];
#pragma unroll
  for (int i = 0; i < 2; ++i)
#pragma unroll
    for (int j = 0; j < 8; ++j) acc[i][j] = {0.f, 0.f, 0.f, 0.f};

  const int arow = tid >> 2;
  const int acg = tid & 3;
  const float* hrow = h + (size_t)srcl[arow] * HD;

  for (int kc = 0; kc < 4; ++kc) {
    const int k0 = kc * 64;
    const float4* s4 = (const float4*)(hrow + k0 + acg * 16);
    float4 q0 = s4[0], q1 = s4[1], q2 = s4[2], q3 = s4[3];
    short8 p0, p1;
    p0[0] = f2bf(q0.x); p0[1] = f2bf(q0.y); p0[2] = f2bf(q0.z); p0[3] = f2bf(q0.w);
    p0[4] = f2bf(q1.x); p0[5] = f2bf(q1.y); p0[6] = f2bf(q1.z); p0[7] = f2bf(q1.w);
    p1[0] = f2bf(q2.x); p1[1] = f2bf(q2.y); p1[2] = f2bf(q2.z); p1[3] = f2bf(q2.w);
    p1[4] = f2bf(q3.x); p1[5] = f2bf(q3.y); p1[6] = f2bf(q3.z); p1[7] = f2bf(q3.w);
    short8* ap = (short8*)&Als[arow * F_AS + acg * 16];
    ap[0] = p0; ap[1] = p1;
#pragma unroll
    for (int i = 0; i < 8; ++i) {
      int f = tid + 256 * i;
      int row = f >> 3, ch = f & 7;
      short8 vb = *(const short8*)(Wfb + row * 256 + k0 + ch * 8);
      *(short8*)&Bls[row * F_BS + ch * 8] = vb;
    }
    __syncthreads();
#pragma unroll
    for (int ks = 0; ks < 2; ++ks) {
      short8 a0 = *(const short8*)&Als[(wm * 32 + cbase) * F_AS + ks * 32 + kg * 8];
      short8 a1 = *(const short8*)&Als[(wm * 32 + 16 + cbase) * F_AS + ks * 32 + kg * 8];
#pragma unroll
      for (int nt = 0; nt < 8; ++nt) {
        short8 b = *(const short8*)&Bls[(wn * 128 + nt * 16 + cbase) * F_BS + ks * 32 + kg * 8];
        acc[0][nt] = __builtin_amdgcn_mfma_f32_16x16x32_bf16(a0, b, acc[0][nt], 0, 0, 0);
        acc[1][nt] = __builtin_amdgcn_mfma_f32_16x16x32_bf16(a1, b, acc[1][nt], 0, 0, 0);
      }
    }
    __syncthreads();
  }
  const int rsub = kg * 4;
#pragma unroll
  for (int nt = 0; nt < 8; ++nt) {
    const int coln = wn * 128 + nt * 16 + cbase;
    const float bias = Ufb[coln];
#pragma unroll
    for (int mt = 0; mt < 2; ++mt) {
#pragma unroll
      for (int j = 0; j < 4; ++j) {
        const int el = wm * 32 + mt * 16 + rsub + j;
        const float fg = sigmoidf_(acc[mt][nt][j] + bias);
        const float cv = c[(size_t)srcl[el] * HD + coln];
        fcb[(size_t)slotl[el] * HD + coln] = f2bf(fg * cv);
      }
    }
  }
}

// ---------------- gather kernel: c_agg (f32 -> out c-half), h_tild (bf16 ->
// first-child slot of fcb, which is dead after this thread's reads) ----------
__global__ __launch_bounds__(256) void gather_kernel(
    const float* __restrict__ h, const int* __restrict__ rp,
    const int* __restrict__ psrc, unsigned short* __restrict__ fcb,
    float* __restrict__ cagg) {
  const int tid = threadIdx.x;
  const int node = blockIdx.x * 32 + (tid >> 3);
  const int cg = tid & 7;  // 32 cols per thread
  const int s0 = rp[node], s1 = rp[node + 1];

  float hs[32], cs[32];
#pragma unroll
  for (int q = 0; q < 32; ++q) { hs[q] = 0.f; cs[q] = 0.f; }

  for (int s = s0; s < s1; ++s) {
    const int src = psrc[s];
    const float4* hp = (const float4*)(h + (size_t)src * HD + cg * 32);
    const short8* fp = (const short8*)(fcb + (size_t)s * HD + cg * 32);
#pragma unroll
    for (int q = 0; q < 8; ++q) {
      float4 v = hp[q];
      hs[4 * q + 0] += v.x; hs[4 * q + 1] += v.y;
      hs[4 * q + 2] += v.z; hs[4 * q + 3] += v.w;
    }
#pragma unroll
    for (int q = 0; q < 4; ++q) {
      short8 w = fp[q];
#pragma unroll
      for (int e = 0; e < 8; ++e) cs[8 * q + e] += bf2f((unsigned short)w[e]);
    }
  }
  // write c_agg (f32) into out c-half
  float4* cp = (float4*)(cagg + (size_t)node * HD + cg * 32);
#pragma unroll
  for (int q = 0; q < 8; ++q) {
    float4 v = {cs[4 * q + 0], cs[4 * q + 1], cs[4 * q + 2], cs[4 * q + 3]};
    cp[q] = v;
  }
  // write h_tild (bf16) into first-child slot
  if (s1 > s0) {
    short8* hd = (short8*)(fcb + (size_t)s0 * HD + cg * 32);
#pragma unroll
    for (int q = 0; q < 4; ++q) {
      short8 p;
#pragma unroll
      for (int e = 0; e < 8; ++e) p[e] = f2bf(hs[8 * q + e]);
      hd[q] = p;
    }
  }
}

// ---------------- iou GEMM: out = gates(x@W^T + h_tild@U^T + b, c_agg) -------
// 64 nodes x 768 cols per block, 512 threads (8 waves: 2M x 4N), K=512.
// B staged from fragment-packed Bp via global_load_lds (lane-linear, 48 KB).
__global__ __launch_bounds__(512, 4) void iou_gemm_kernel(
    const float* __restrict__ x, const unsigned short* __restrict__ Bp,
    const float* __restrict__ bperm, const int* __restrict__ rp,
    const unsigned short* __restrict__ fcb, const char* __restrict__ zpage,
    float* __restrict__ out) {
  __shared__ __align__(16) unsigned short Bls[48 * 512];  // 49152 B

  const int tid = threadIdx.x;
  const int lane = tid & 63;
  const int wv = tid >> 6;
  const int wm = wv >> 2, wn = wv & 3;
  const int cbase = lane & 15;
  const int kg = lane >> 4;
  const int r0 = blockIdx.x * 64;
  const int row0 = r0 + wm * 32 + cbase;
  const int row1 = row0 + 16;

  const int sa0 = rp[row0], ea0 = rp[row0 + 1];
  const int sa1 = rp[row1], ea1 = rp[row1 + 1];
  const char* pH0 = (ea0 > sa0) ? (const char*)(fcb + (size_t)sa0 * HD) : zpage;
  const char* pH1 = (ea1 > sa1) ? (const char*)(fcb + (size_t)sa1 * HD) : zpage;
  const float* pX0 = x + (size_t)row0 * HD;
  const float* pX1 = x + (size_t)row1 * HD;

  f32x4 acc[2][12];
#pragma unroll
  for (int m = 0; m < 2; ++m)
#pragma unroll
    for (int t = 0; t < 12; ++t) acc[m][t] = {0.f, 0.f, 0.f, 0.f};

  for (int kc = 0; kc < 16; ++kc) {
    // stage 48 KB of packed B: each thread 6 x 16B, lane-linear
    const char* gB = (const char*)Bp + kc * 49152 + wv * 1024 + lane * 16;
    char* lB = (char*)Bls + wv * 1024;
#ifdef HAVE_GLDS
#pragma unroll
    for (int i = 0; i < 6; ++i) gload_lds16(gB + i * 8192, lB + i * 8192);
#else
#pragma unroll
    for (int i = 0; i < 6; ++i) {
      short8 v = *(const short8*)(gB + i * 8192);
      *(short8*)(lB + lane * 16 + i * 8192) = v;
    }
#endif
    // A fragments (global; overlap with staging)
    short8 a0, a1;
    const int k0 = (kc & 7) * 32;
    if (kc < 8) {
      float4 u0 = *(const float4*)(pX0 + k0 + kg * 8);
      float4 u1 = *(const float4*)(pX0 + k0 + kg * 8 + 4);
      float4 u2 = *(const float4*)(pX1 + k0 + kg * 8);
      float4 u3 = *(const float4*)(pX1 + k0 + kg * 8 + 4);
      a0[0] = f2bf(u0.x); a0[1] = f2bf(u0.y); a0[2] = f2bf(u0.z); a0[3] = f2bf(u0.w);
      a0[4] = f2bf(u1.x); a0[5] = f2bf(u1.y); a0[6] = f2bf(u1.z); a0[7] = f2bf(u1.w);
      a1[0] = f2bf(u2.x); a1[1] = f2bf(u2.y); a1[2] = f2bf(u2.z); a1[3] = f2bf(u2.w);
      a1[4] = f2bf(u3.x); a1[5] = f2bf(u3.y); a1[6] = f2bf(u3.z); a1[7] = f2bf(u3.w);
    } else {
      a0 = *(const short8*)(pH0 + k0 * 2 + kg * 16);
      a1 = *(const short8*)(pH1 + k0 * 2 + kg * 16);
    }
    __syncthreads();
    const char* bbase = (const char*)Bls + (wn * 12) * 1024 + lane * 16;
#pragma unroll
    for (int tt = 0; tt < 12; ++tt) {
      short8 b = *(const short8*)(bbase + tt * 1024);
      acc[0][tt] = __builtin_amdgcn_mfma_f32_16x16x32_bf16(a0, b, acc[0][tt], 0, 0, 0);
      acc[1][tt] = __builtin_amdgcn_mfma_f32_16x16x32_bf16(a1, b, acc[1][tt], 0, 0, 0);
    }
    __syncthreads();
  }

  // epilogue: gate triples (i,o,u) are consecutive tiles 3t,3t+1,3t+2
  float* outc = out + (size_t)NN * HD;
  const int rbase = wm * 32 + kg * 4;
#pragma unroll
  for (int t3 = 0; t3 < 4; ++t3) {
    const int T = wn * 12 + 3 * t3;
    const float bi = bperm[(T + 0) * 16 + cbase];
    const float bo = bperm[(T + 1) * 16 + cbase];
    const float bu = bperm[(T + 2) * 16 + cbase];
    const int j = (wn * 4 + t3) * 16 + cbase;
#pragma unroll
    for (int mf = 0; mf < 2; ++mf) {
#pragma unroll
      for (int jr = 0; jr < 4; ++jr) {
        const int rl = rbase + mf * 16 + jr;
        const size_t idx = (size_t)(r0 + rl) * HD + j;
        const float iv = sigmoidf_(acc[mf][3 * t3 + 0][jr] + bi);
        const float ov = sigmoidf_(acc[mf][3 * t3 + 1][jr] + bo);
        const float uv = tanhf_(acc[mf][3 * t3 + 2][jr] + bu);
        const float cn = iv * uv + outc[idx];
        out[idx] = ov * tanhf_(cn);
        outc[idx] = cn;
      }
    }
  }
}

// ================= fallback path (R1 kernels, used when ws is too small) ======
__global__ __launch_bounds__(256) void edge_kernel(
    const float* __restrict__ h, const float* __restrict__ c,
    const unsigned short* __restrict__ Wfb, const float* __restrict__ Ufb,
    const int* __restrict__ esrc, const int* __restrict__ edst,
    float* h_tild, float* c_agg) {
  __shared__ __align__(16) unsigned short Als[64 * F_AS];
  __shared__ __align__(16) unsigned short Bls[256 * F_BS];
  __shared__ int srcl[64], dstl[64];

  const int tid = threadIdx.x;
  const int e0 = blockIdx.x * 64;
  if (tid < 64) { srcl[tid] = esrc[e0 + tid]; dstl[tid] = edst[e0 + tid]; }
  __syncthreads();

  const int lane = tid & 63;
  const int wv = tid >> 6;
  const int wm = wv >> 1, wn = wv & 1;
  const int cbase = lane & 15;
  const int kg = lane >> 4;

  f32x4 acc[2][8];
#pragma unroll
  for (int i = 0; i < 2; ++i)
#pragma unroll
    for (int j = 0; j < 8; ++j) acc[i][j] = {0.f, 0.f, 0.f, 0.f};

  const int arow = tid >> 2;
  const int acg = tid & 3;
  const float* hrow = h + (size_t)srcl[arow] * HD;
  float* htrow = h_tild + (size_t)dstl[arow] * HD;

  for (int kc = 0; kc < 4; ++kc) {
    const int k0 = kc * 64;
    const float4* s4 = (const float4*)(hrow + k0 + acg * 16);
    float4 q0 = s4[0], q1 = s4[1], q2 = s4[2], q3 = s4[3];
    short8 p0, p1;
    p0[0] = f2bf(q0.x); p0[1] = f2bf(q0.y); p0[2] = f2bf(q0.z); p0[3] = f2bf(q0.w);
    p0[4] = f2bf(q1.x); p0[5] = f2bf(q1.y); p0[6] = f2bf(q1.z); p0[7] = f2bf(q1.w);
    p1[0] = f2bf(q2.x); p1[1] = f2bf(q2.y); p1[2] = f2bf(q2.z); p1[3] = f2bf(q2.w);
    p1[4] = f2bf(q3.x); p1[5] = f2bf(q3.y); p1[6] = f2bf(q3.z); p1[7] = f2bf(q3.w);
    short8* ap = (short8*)&Als[arow * F_AS + acg * 16];
    ap[0] = p0; ap[1] = p1;
    {
      float* hp = htrow + k0 + acg * 16;
      atomAddF(hp + 0, q0.x);  atomAddF(hp + 1, q0.y);
      atomAddF(hp + 2, q0.z);  atomAddF(hp + 3, q0.w);
      atomAddF(hp + 4, q1.x);  atomAddF(hp + 5, q1.y);
      atomAddF(hp + 6, q1.z);  atomAddF(hp + 7, q1.w);
      atomAddF(hp + 8, q2.x);  atomAddF(hp + 9, q2.y);
      atomAddF(hp + 10, q2.z); atomAddF(hp + 11, q2.w);
      atomAddF(hp + 12, q3.x); atomAddF(hp + 13, q3.y);
      atomAddF(hp + 14, q3.z); atomAddF(hp + 15, q3.w);
    }
#pragma unroll
    for (int i = 0; i < 8; ++i) {
      int f = tid + 256 * i;
      int row = f >> 3, ch = f & 7;
      short8 vb = *(const short8*)(Wfb + row * 256 + k0 + ch * 8);
      *(short8*)&Bls[row * F_BS + ch * 8] = vb;
    }
    __syncthreads();
#pragma unroll
    for (int ks = 0; ks < 2; ++ks) {
      short8 a0 = *(const short8*)&Als[(wm * 32 + cbase) * F_AS + ks * 32 + kg * 8];
      short8 a1 = *(const short8*)&Als[(wm * 32 + 16 + cbase) * F_AS + ks * 32 + kg * 8];
#pragma unroll
      for (int nt = 0; nt < 8; ++nt) {
        short8 b = *(const short8*)&Bls[(wn * 128 + nt * 16 + cbase) * F_BS + ks * 32 + kg * 8];
        acc[0][nt] = __builtin_amdgcn_mfma_f32_16x16x32_bf16(a0, b, acc[0][nt], 0, 0, 0);
        acc[1][nt] = __builtin_amdgcn_mfma_f32_16x16x32_bf16(a1, b, acc[1][nt], 0, 0, 0);
      }
    }
    __syncthreads();
  }
  const int rsub = kg * 4;
#pragma unroll
  for (int nt = 0; nt < 8; ++nt) {
    const int coln = wn * 128 + nt * 16 + cbase;
    const float bias = Ufb[coln];
#pragma unroll
    for (int mt = 0; mt < 2; ++mt) {
#pragma unroll
      for (int j = 0; j < 4; ++j) {
        const int el = wm * 32 + mt * 16 + rsub + j;
        const float fg = sigmoidf_(acc[mt][nt][j] + bias);
        const float cv = c[(size_t)srcl[el] * HD + coln];
        atomAddF(c_agg + (size_t)dstl[el] * HD + coln, fg * cv);
      }
    }
  }
}

#define I_AS 40
#define I_BS 40

__global__ __launch_bounds__(256) void iou_kernel(
    const float* __restrict__ x, const unsigned short* __restrict__ Wioub,
    const unsigned short* __restrict__ Uioub, const float* __restrict__ bperm,
    float* out) {
  __shared__ __align__(16) unsigned short Als[32 * I_AS];
  __shared__ __align__(16) unsigned short Bls[768 * I_BS];

  const int tid = threadIdx.x;
  const int lane = tid & 63;
  const int wv = tid >> 6;
  const int wm = wv >> 1, wn = wv & 1;
  const int cbase = lane & 15;
  const int kg = lane >> 4;
  const int r0 = blockIdx.x * 32;

  float* h_tild = out;
  float* c_agg = out + (size_t)NN * HD;

  f32x4 acc[24];
#pragma unroll
  for (int t = 0; t < 24; ++t) acc[t] = {0.f, 0.f, 0.f, 0.f};

  const int arow = tid >> 3;
  const int acg = tid & 7;

  for (int pass = 0; pass < 2; ++pass) {
    const float* As = pass ? h_tild : x;
    const unsigned short* Bs = pass ? Uioub : Wioub;
    for (int kc = 0; kc < 8; ++kc) {
      const int k0 = kc * 32;
      float4 q = *(const float4*)(As + (size_t)(r0 + arow) * HD + k0 + acg * 4);
      short4v p;
      p[0] = f2bf(q.x); p[1] = f2bf(q.y); p[2] = f2bf(q.z); p[3] = f2bf(q.w);
      *(short4v*)&Als[arow * I_AS + acg * 4] = p;
#pragma unroll
      for (int i = 0; i < 12; ++i) {
        int f = tid + 256 * i;
        int row = f >> 2, ch = f & 3;
        short8 vb = *(const short8*)(Bs + row * 256 + k0 + ch * 8);
        *(short8*)&Bls[row * I_BS + ch * 8] = vb;
      }
      __syncthreads();
      short8 a = *(const short8*)&Als[(wm * 16 + cbase) * I_AS + kg * 8];
#pragma unroll
      for (int tt = 0; tt < 24; ++tt) {
        short8 b = *(const short8*)&Bls[((wn * 24 + tt) * 16 + cbase) * I_BS + kg * 8];
        acc[tt] = __builtin_amdgcn_mfma_f32_16x16x32_bf16(a, b, acc[tt], 0, 0, 0);
      }
      __syncthreads();
    }
  }
  const int rsub = kg * 4;
#pragma unroll
  for (int t3 = 0; t3 < 8; ++t3) {
    const int T = wn * 24 + 3 * t3;
    const float bi = bperm[(T + 0) * 16 + cbase];
    const float bo = bperm[(T + 1) * 16 + cbase];
    const float bu = bperm[(T + 2) * 16 + cbase];
    const int j = (wn * 8 + t3) * 16 + cbase;
#pragma unroll
    for (int jr = 0; jr < 4; ++jr) {
      const int r = r0 + wm * 16 + rsub + jr;
      const size_t idx = (size_t)r * HD + j;
      const float iv = sigmoidf_(acc[3 * t3 + 0][jr] + bi);
      const float ov = sigmoidf_(acc[3 * t3 + 1][jr] + bo);
      const float uv = tanhf_(acc[3 * t3 + 2][jr] + bu);
      const float cn = iv * uv + c_agg[idx];
      out[idx] = ov * tanhf_(cn);
      c_agg[idx] = cn;
    }
  }
}

extern "C" void kernel_launch(void* const* d_in, const int* in_sizes, int n_in,
                              void* d_out, int out_size, void* d_ws, size_t ws_size,
                              hipStream_t stream) {
  const float* x    = (const float*)d_in[0];
  const float* h    = (const float*)d_in[1];
  const float* c    = (const float*)d_in[2];
  const float* Wiou = (const float*)d_in[3];
  const float* Uiou = (const float*)d_in[4];
  const float* biou = (const float*)d_in[5];
  const float* Ufw  = (const float*)d_in[6];
  const float* Ufb  = (const float*)d_in[7];
  const int* esrc   = (const int*)d_in[8];
  const int* edst   = (const int*)d_in[9];
  float* out = (float*)d_out;

  char* ws = (char*)d_ws;
  unsigned short* Wfb   = (unsigned short*)(ws + OFF_WFB);
  unsigned short* Bp    = (unsigned short*)(ws + OFF_BP);
  float* bperm          = (float*)(ws + OFF_BPERM);

  if (ws_size >= WS_NEED) {
    int* rpp  = (int*)(ws + OFF_ROWPTR);
    int* nxt  = (int*)(ws + OFF_NEXT);
    int* slot = (int*)(ws + OFF_SLOT);
    int* psrc = (int*)(ws + OFF_PSRC);
    int* bsum = (int*)(ws + OFF_BSUM);
    char* zpage = ws + OFF_ZERO;
    unsigned short* fcb = (unsigned short*)(ws + OFF_FC);

    hipMemsetAsync(nxt, 0, (size_t)NN * sizeof(int), stream);
    hipMemsetAsync(zpage, 0, 1024, stream);
    prep_kernel<<<1795, 256, 0, stream>>>(Ufw, Wiou, Uiou, biou, Wfb, Bp, bperm);
    hist_kernel<<<(NE + 255) / 256, 256, 0, stream>>>(edst, nxt);
    scan_part<<<(NN + 1023) / 1024, 256, 0, stream>>>(nxt, rpp, bsum);
    scan_top<<<1, 256, 0, stream>>>(bsum, rpp, (NN + 1023) / 1024);
    scan_add<<<(NN + 1023) / 1024, 256, 0, stream>>>(rpp, bsum, nxt);
    scatter_kernel<<<(NE + 255) / 256, 256, 0, stream>>>(esrc, edst, nxt, slot, psrc);
    edge_fc_kernel<<<NE / 64, 256, 0, stream>>>(h, c, Wfb, Ufb, esrc, slot, fcb);
    gather_kernel<<<NN / 32, 256, 0, stream>>>(h, rpp, psrc, fcb, out + (size_t)NN * HD);
    iou_gemm_kernel<<<NN / 64, 512, 0, stream>>>(x, Bp, bperm, rpp, fcb, zpage, out);
  } else {
    // fallback: R1 scatter-atomic path (row-major permuted weights in BP region)
    unsigned short* Wioub = (unsigned short*)(ws + OFF_BP);
    unsigned short* Uioub = (unsigned short*)(ws + OFF_BP + 393216);
    hipMemsetAsync(d_out, 0, (size_t)out_size * sizeof(float), stream);
    prep_fb_kernel<<<1795, 256, 0, stream>>>(Ufw, Wiou, Uiou, biou, Wfb, Wioub, Uioub, bperm);
    edge_kernel<<<NE / 64, 256, 0, stream>>>(h, c, Wfb, Ufb, esrc, edst,
                                             out, out + (size_t)NN * HD);
    iou_kernel<<<NN / 32, 256, 0, stream>>>(x, Wioub, Uioub, bperm, out);
  }
}